// Round 10
// baseline (209.272 us; speedup 1.0000x reference)
//
#include <hip/hip_runtime.h>

#define B_  2
#define T_  2048
#define C_  1024
#define H_  16
#define HS_ 64
#define M_  4096
#define N_  1024
#define K_  1024

typedef float floatx4 __attribute__((ext_vector_type(4)));
typedef short bf16x8  __attribute__((ext_vector_type(8)));

__device__ __forceinline__ float bf2f(unsigned short u) {
    return __uint_as_float(((unsigned int)u) << 16);
}
__device__ __forceinline__ unsigned short f2bf(float f) {
    unsigned int u = __float_as_uint(f);
    return (unsigned short)((u + 0x7fffu + ((u >> 16) & 1u)) >> 16);
}
__device__ __forceinline__ unsigned int pack2(float a, float b) {
    return (unsigned int)f2bf(a) | ((unsigned int)f2bf(b) << 16);
}
// truncating bf16 pair pack: one v_perm_b32
__device__ __forceinline__ unsigned int pack2t(float a, float b) {
    return __builtin_amdgcn_perm(__float_as_uint(b), __float_as_uint(a), 0x07060302u);
}
// async global->LDS, 16B per lane; lds dest = wave-uniform base + lane*16
__device__ __forceinline__ void async16(const unsigned short* g, unsigned short* l) {
    __builtin_amdgcn_global_load_lds(
        (const __attribute__((address_space(1))) unsigned int*)g,
        (__attribute__((address_space(3))) unsigned int*)l, 16, 0, 0);
}

// ---------------------------------------------------------------------------
// Prep (merged): blocks 0..4095 convert x fp32->bf16; blocks 4096..5119
// transpose+convert weights. grid 5120, block 256.
// ---------------------------------------------------------------------------
__global__ __launch_bounds__(256) void prep_kernel(
    const float* __restrict__ x,
    const float* __restrict__ w0, const float* __restrict__ w1,
    const float* __restrict__ w2, const float* __restrict__ w3,
    unsigned short* __restrict__ xb, unsigned short* __restrict__ wTall)
{
    __shared__ float tile[64][65];
    const int bid = blockIdx.x;
    const int t = threadIdx.x;
    if (bid < 4096) {
        const size_t i = ((size_t)bid * 256 + t) * 4;
        const float4 v = *(const float4*)(x + i);
        ushort4 st;
        st.x = f2bf(v.x); st.y = f2bf(v.y); st.z = f2bf(v.z); st.w = f2bf(v.w);
        *(ushort4*)(xb + i) = st;
        return;
    }
    const int zb = bid - 4096;
    const int z = zb >> 8, rem = zb & 255;
    const float* w = (z == 0) ? w0 : (z == 1) ? w1 : (z == 2) ? w2 : w3;
    unsigned short* wT = wTall + ((size_t)z << 20);
    const int n0 = (rem & 15) * 64, k0 = (rem >> 4) * 64;

    const int r = t >> 2, cq = (t & 3) * 16;
    const float4* src = (const float4*)(w + (size_t)(k0 + r) * N_ + n0 + cq);
    const float4 v0 = src[0], v1 = src[1], v2 = src[2], v3 = src[3];
    tile[r][cq+0]=v0.x; tile[r][cq+1]=v0.y; tile[r][cq+2]=v0.z; tile[r][cq+3]=v0.w;
    tile[r][cq+4]=v1.x; tile[r][cq+5]=v1.y; tile[r][cq+6]=v1.z; tile[r][cq+7]=v1.w;
    tile[r][cq+8]=v2.x; tile[r][cq+9]=v2.y; tile[r][cq+10]=v2.z; tile[r][cq+11]=v2.w;
    tile[r][cq+12]=v3.x; tile[r][cq+13]=v3.y; tile[r][cq+14]=v3.z; tile[r][cq+15]=v3.w;
    __syncthreads();

    const int rn = t >> 2, ck = (t & 3) * 16;
    unsigned int o[8];
#pragma unroll
    for (int ii = 0; ii < 8; ii++)
        o[ii] = pack2(tile[ck + 2*ii][rn], tile[ck + 2*ii + 1][rn]);
    unsigned short* dst = wT + (size_t)(n0 + rn) * K_ + k0 + ck;
    *(uint4*)dst       = make_uint4(o[0], o[1], o[2], o[3]);
    *(uint4*)(dst + 8) = make_uint4(o[4], o[5], o[6], o[7]);
}

// ---------------------------------------------------------------------------
// Kernel 1: fused QKV GEMM + RoPE. 64(M)x128(N) tiles, BK=32, explicit LDS
// double-buffer: loads issued one full iteration before the barrier that
// drains them. grid (24, 64) = 1536 blocks (6/CU @ 24KB LDS), block 256.
// ---------------------------------------------------------------------------
__global__ __launch_bounds__(256) void qkv_gemm(
    const unsigned short* __restrict__ xb, const unsigned short* __restrict__ wT,
    const float* __restrict__ bq, const float* __restrict__ bk,
    const float* __restrict__ bv,
    unsigned short* __restrict__ qb, unsigned short* __restrict__ kb,
    unsigned short* __restrict__ vb)
{
    __shared__ unsigned short As[2][64 * 32];    // [buf][m][k]
    __shared__ unsigned short Bs[2][128 * 32];   // [buf][n][k]

    const int tid  = threadIdx.x;
    const int lane = tid & 63;
    const int wave = tid >> 6;
    const int p  = blockIdx.x >> 3;
    const int n0 = (blockIdx.x & 7) * 128;
    const int m0 = blockIdx.y * 64;
    const float* bias = (p == 0) ? bq : (p == 1) ? bk : bv;

    // staging: lane l -> row l>>2, 8-elem chunk l&3 (matches lane*16B dest)
    const int lrow = lane >> 2, lch = (lane & 3) * 8;
    const unsigned short* agA = xb + (size_t)(m0 + wave * 16 + lrow) * K_ + lch;
    const unsigned short* wb  = wT + ((size_t)p << 20);
    const unsigned short* bg0 = wb + (size_t)(n0 + wave * 32 + lrow) * K_ + lch;
    const unsigned short* bg1 = bg0 + (size_t)16 * K_;
    const int ldsA  = (wave * 16) * 32;
    const int ldsB0 = (wave * 32) * 32;
    const int ldsB1 = (wave * 32 + 16) * 32;

    const int fr = lane & 15;
    const int fk = (lane >> 4) * 8;
    const int wr2 = wave >> 1, wc2 = wave & 1;

    floatx4 acc[2][4];
#pragma unroll
    for (int i = 0; i < 2; i++)
#pragma unroll
        for (int j = 0; j < 4; j++) acc[i][j] = (floatx4){0.f, 0.f, 0.f, 0.f};

    // prologue: stage k0=0 into buffer 0
    async16(agA, &As[0][ldsA]);
    async16(bg0, &Bs[0][ldsB0]);
    async16(bg1, &Bs[0][ldsB1]);

    for (int k0 = 0; k0 < K_; k0 += 32) {
        const int cur = (k0 >> 5) & 1;
        __syncthreads();      // drains vmcnt(0): buf[cur] ready (issued 1 iter ago)
        if (k0 + 32 < K_) {   // stage next tile into other buffer
            const int nxt = cur ^ 1;
            async16(agA + k0 + 32, &As[nxt][ldsA]);
            async16(bg0 + k0 + 32, &Bs[nxt][ldsB0]);
            async16(bg1 + k0 + 32, &Bs[nxt][ldsB1]);
        }

        bf16x8 af[2], bfr[4];
#pragma unroll
        for (int i = 0; i < 2; i++)
            af[i] = *(const bf16x8*)&As[cur][(wr2 * 32 + i * 16 + fr) * 32 + fk];
#pragma unroll
        for (int j = 0; j < 4; j++)
            bfr[j] = *(const bf16x8*)&Bs[cur][(wc2 * 64 + j * 16 + fr) * 32 + fk];
#pragma unroll
        for (int i = 0; i < 2; i++)
#pragma unroll
            for (int j = 0; j < 4; j++)
                acc[i][j] = __builtin_amdgcn_mfma_f32_16x16x32_bf16(
                    af[i], bfr[j], acc[i][j], 0, 0, 0);
    }

    const int rbase = (lane >> 4) * 4;
    const int h = (n0 + wc2 * 64) >> 6;     // lane's 4 cols share one head
    if (p == 2) {    // V transposed: [B,H,HS,T]
#pragma unroll
        for (int j = 0; j < 4; j++) {
            const int col = n0 + wc2 * 64 + j * 16 + fr;
            const float bz = bias[col];
            const int d = col & 63;
#pragma unroll
            for (int i = 0; i < 2; i++) {
                const int row0 = m0 + wr2 * 32 + i * 16 + rbase;
                const int bb = row0 >> 11, tt = row0 & 2047;
                ushort4 st;
                st.x = f2bf(acc[i][j][0] + bz);
                st.y = f2bf(acc[i][j][1] + bz);
                st.z = f2bf(acc[i][j][2] + bz);
                st.w = f2bf(acc[i][j][3] + bz);
                *(ushort4*)&vb[((size_t)(bb * H_ + h) * HS_ + d) * T_ + tt] = st;
            }
        }
    } else {
        unsigned short* out = (p == 0) ? qb : kb;
        const float qsc = (p == 0) ? 0.18033688011111772f : 1.0f;  // 0.125*log2(e)
        const float bz0 = bias[n0 + wc2 * 64 + fr];
        const float bz1 = bias[n0 + wc2 * 64 + 16 + fr];
        const float bz2 = bias[n0 + wc2 * 64 + 32 + fr];
        const float bz3 = bias[n0 + wc2 * 64 + 48 + fr];
        const float nl = -0.41524101186279297f;   // -log2(10000)/32
        const float if0 = exp2f((float)fr * nl);
        const float if1 = exp2f((float)(fr + 16) * nl);
#pragma unroll
        for (int i = 0; i < 2; i++) {
#pragma unroll
            for (int pr = 0; pr < 4; pr++) {
                const int row = m0 + wr2 * 32 + i * 16 + rbase + pr;
                const int bb = row >> 11, tt = row & 2047;
                float s0, c0, s1, c1;
                __sincosf((float)tt * if0, &s0, &c0);
                __sincosf((float)tt * if1, &s1, &c1);
                const float v0 = acc[i][0][pr] + bz0;
                const float v1 = acc[i][1][pr] + bz1;
                const float v2 = acc[i][2][pr] + bz2;
                const float v3 = acc[i][3][pr] + bz3;
                unsigned short* ob = out + ((size_t)(bb * H_ + h) * T_ + tt) * HS_ + fr;
                ob[0]  = f2bf((v0 * c0 - v2 * s0) * qsc);
                ob[16] = f2bf((v1 * c1 - v3 * s1) * qsc);
                ob[32] = f2bf((v2 * c0 + v0 * s0) * qsc);
                ob[48] = f2bf((v3 * c1 + v1 * s1) * qsc);
            }
        }
    }
}

// ---------------------------------------------------------------------------
// Kernel 3: MFMA flash attention, split-K flash-decoding (unchanged).
// grid (32, 48), block 256.
// ---------------------------------------------------------------------------
__global__ __launch_bounds__(256) void attn_kernel(
    const unsigned short* __restrict__ qb, const unsigned short* __restrict__ kb,
    const unsigned short* __restrict__ vt, unsigned short* __restrict__ yb,
    unsigned short* __restrict__ Opart, float* __restrict__ Mpart)
{
    __shared__ unsigned short Ks[2][64 * 64];
    __shared__ unsigned short Vs[2][64 * 64];
    __shared__ unsigned short Ps[4][16 * 64];

    const int bh = blockIdx.x;
    const int b = bh >> 4, h = bh & 15;
    const int s = 47 - (int)blockIdx.y;          // LPT: biggest first
    int qt, ktlo, kthi, half;
    bool split;
    if (s < 16) { qt = s; ktlo = 0; kthi = qt; half = 0; split = false; }
    else {
        const int idx = s - 16;
        qt = 16 + (idx >> 1); half = idx & 1;
        const int nf = (qt + 2) >> 1;
        ktlo = half ? nf : 0;
        kthi = half ? qt : nf - 1;
        split = true;
    }
    const int r0 = qt * 64;
    const int tid  = threadIdx.x;
    const int lane = tid & 63;
    const int wave = tid >> 6;
    const int l4   = lane & 15;
    const int quad = lane >> 4;

    const int qrow_g = r0 + wave * 16 + l4;

    bf16x8 qf[2];
    {
        const unsigned short* qp = qb + ((size_t)bh * T_ + qrow_g) * HS_ + quad * 8;
        qf[0] = *(const bf16x8*)(qp);
        qf[1] = *(const bf16x8*)(qp + 32);
    }

    floatx4 o[4];
#pragma unroll
    for (int g = 0; g < 4; g++) o[g] = (floatx4){0.f, 0.f, 0.f, 0.f};
    float m = -1e30f, l = 0.f;

    const int srow = tid >> 2;
    const int sc16 = (tid & 3) * 16;
    const int ssw  = (srow & 7) * 8;
    const int psw  = (l4 & 7) * 8;

    const unsigned short* kp = kb + ((size_t)bh * T_ + srow) * HS_ + sc16;
    const unsigned short* vp = vt + ((size_t)(bh * 64 + srow)) * T_ + sc16;

    uint4 rk0 = *(const uint4*)(kp + (size_t)ktlo * 64 * HS_);
    uint4 rk1 = *(const uint4*)(kp + (size_t)ktlo * 64 * HS_ + 8);
    uint4 rv0 = *(const uint4*)(vp + ktlo * 64);
    uint4 rv1 = *(const uint4*)(vp + ktlo * 64 + 8);
    *(uint4*)&Ks[0][srow * 64 + ( sc16      ^ ssw)] = rk0;
    *(uint4*)&Ks[0][srow * 64 + ((sc16 + 8) ^ ssw)] = rk1;
    *(uint4*)&Vs[0][srow * 64 + ( sc16      ^ ssw)] = rv0;
    *(uint4*)&Vs[0][srow * 64 + ((sc16 + 8) ^ ssw)] = rv1;

    for (int kt = ktlo; kt <= kthi; kt++) {
        const int cur = (kt - ktlo) & 1;
        if (kt < kthi) {
            const unsigned short* kpn = kp + (size_t)(kt + 1) * (64 * HS_);
            const unsigned short* vpn = vp + (kt + 1) * 64;
            rk0 = *(const uint4*)kpn;
            rk1 = *(const uint4*)(kpn + 8);
            rv0 = *(const uint4*)vpn;
            rv1 = *(const uint4*)(vpn + 8);
        }
        __syncthreads();

        floatx4 sf[4];
#pragma unroll
        for (int mg = 0; mg < 4; mg++) {
            const int key = mg * 16 + l4;
            const int ksw = (key & 7) * 8;
            const bf16x8 a0 = *(const bf16x8*)&Ks[cur][key * 64 + ( (quad * 8)       ^ ksw)];
            const bf16x8 a1 = *(const bf16x8*)&Ks[cur][key * 64 + (((quad * 8) + 32) ^ ksw)];
            floatx4 z = (floatx4){0.f, 0.f, 0.f, 0.f};
            z = __builtin_amdgcn_mfma_f32_16x16x32_bf16(a0, qf[0], z, 0, 0, 0);
            z = __builtin_amdgcn_mfma_f32_16x16x32_bf16(a1, qf[1], z, 0, 0, 0);
            sf[mg] = z;
        }

        if (kt == qt) {
#pragma unroll
            for (int mg = 0; mg < 4; mg++)
#pragma unroll
                for (int r = 0; r < 4; r++)
                    if (kt * 64 + 16 * mg + quad * 4 + r > qrow_g)
                        sf[mg][r] = -1e30f;
        }

        float tm = sf[0][0];
#pragma unroll
        for (int mg = 0; mg < 4; mg++)
#pragma unroll
            for (int r = 0; r < 4; r++) tm = fmaxf(tm, sf[mg][r]);
        tm = fmaxf(tm, __shfl_xor(tm, 16));
        tm = fmaxf(tm, __shfl_xor(tm, 32));
        const float mnew  = fmaxf(m, tm);
        const float alpha = __builtin_amdgcn_exp2f(m - mnew);

        float p[4][4];
        float ps = 0.f;
#pragma unroll
        for (int mg = 0; mg < 4; mg++)
#pragma unroll
            for (int r = 0; r < 4; r++) {
                p[mg][r] = __builtin_amdgcn_exp2f(sf[mg][r] - mnew);
                ps += p[mg][r];
            }
        ps += __shfl_xor(ps, 16);
        ps += __shfl_xor(ps, 32);
        l = l * alpha + ps;
        m = mnew;
#pragma unroll
        for (int g = 0; g < 4; g++) o[g] = o[g] * alpha;

#pragma unroll
        for (int mg = 0; mg < 4; mg++) {
            const int kb4 = 16 * mg + quad * 4;
            const int off = ((kb4 & ~7) ^ psw) | (kb4 & 7);
            uint2 w;
            w.x = pack2t(p[mg][0], p[mg][1]);
            w.y = pack2t(p[mg][2], p[mg][3]);
            *(uint2*)&Ps[wave][l4 * 64 + off] = w;
        }

        const bf16x8 pf0 = *(const bf16x8*)&Ps[wave][l4 * 64 + ( (quad * 8)       ^ psw)];
        const bf16x8 pf1 = *(const bf16x8*)&Ps[wave][l4 * 64 + (((quad * 8) + 32) ^ psw)];
#pragma unroll
        for (int g = 0; g < 4; g++) {
            const int vd  = g * 16 + l4;
            const int vsw = (vd & 7) * 8;
            const bf16x8 va0 = *(const bf16x8*)&Vs[cur][vd * 64 + ( (quad * 8)       ^ vsw)];
            const bf16x8 va1 = *(const bf16x8*)&Vs[cur][vd * 64 + (((quad * 8) + 32) ^ vsw)];
            o[g] = __builtin_amdgcn_mfma_f32_16x16x32_bf16(va0, pf0, o[g], 0, 0, 0);
            o[g] = __builtin_amdgcn_mfma_f32_16x16x32_bf16(va1, pf1, o[g], 0, 0, 0);
        }

        if (kt < kthi) {
            const int nxt = cur ^ 1;
            *(uint4*)&Ks[nxt][srow * 64 + ( sc16      ^ ssw)] = rk0;
            *(uint4*)&Ks[nxt][srow * 64 + ((sc16 + 8) ^ ssw)] = rk1;
            *(uint4*)&Vs[nxt][srow * 64 + ( sc16      ^ ssw)] = rv0;
            *(uint4*)&Vs[nxt][srow * 64 + ((sc16 + 8) ^ ssw)] = rv1;
        }
    }

    if (!split) {
        const float invl = 1.f / l;
        unsigned short* yrow = yb + ((size_t)(b * T_ + qrow_g) * H_ + h) * HS_;
#pragma unroll
        for (int g = 0; g < 4; g++) {
            ushort4 st;
            st.x = f2bf(o[g][0] * invl);
            st.y = f2bf(o[g][1] * invl);
            st.z = f2bf(o[g][2] * invl);
            st.w = f2bf(o[g][3] * invl);
            *(ushort4*)&yrow[16 * g + quad * 4] = st;
        }
    } else {
        const int u  = (bh * 16 + (qt - 16)) * 2 + half;
        const int rl = wave * 16 + l4;
        unsigned short* Op = Opart + (size_t)u * 4096 + rl * 64;
#pragma unroll
        for (int g = 0; g < 4; g++) {
            ushort4 st;
            st.x = f2bf(o[g][0]);
            st.y = f2bf(o[g][1]);
            st.z = f2bf(o[g][2]);
            st.w = f2bf(o[g][3]);
            *(ushort4*)&Op[16 * g + quad * 4] = st;
        }
        if (quad == 0) {
            float* ml = Mpart + (size_t)u * 128;
            ml[rl]      = m;
            ml[64 + rl] = l;
        }
    }
}

// ---------------------------------------------------------------------------
// Kernel 3b: merge split-K partials. grid 512, block 256.
// ---------------------------------------------------------------------------
__global__ __launch_bounds__(256) void attn_combine(
    const unsigned short* __restrict__ Opart, const float* __restrict__ Mpart,
    unsigned short* __restrict__ yb)
{
    const int u  = blockIdx.x;
    const int bh = u >> 4, qt = 16 + (u & 15);
    const int b = bh >> 4, h = bh & 15;
    const int t = threadIdx.x;
    const int r = t >> 2, c = (t & 3) * 16;

    const float* ml1 = Mpart + (size_t)(u * 2) * 128;
    const float* ml2 = ml1 + 128;
    const float m1 = ml1[r], l1 = ml1[64 + r];
    const float m2 = ml2[r], l2 = ml2[64 + r];
    const float M  = fmaxf(m1, m2);
    const float w1 = __builtin_amdgcn_exp2f(m1 - M);
    const float w2 = __builtin_amdgcn_exp2f(m2 - M);
    const float inv = 1.f / (l1 * w1 + l2 * w2);
    const float a1 = w1 * inv, a2 = w2 * inv;

    const unsigned short* O1 = Opart + (size_t)(u * 2)     * 4096 + r * 64 + c;
    const unsigned short* O2 = Opart + (size_t)(u * 2 + 1) * 4096 + r * 64 + c;
    unsigned short* yrow = yb + ((size_t)(b * T_ + qt * 64 + r) * H_ + h) * HS_ + c;

#pragma unroll
    for (int j = 0; j < 2; j++) {
        const uint4 u1 = *(const uint4*)(O1 + 8 * j);
        const uint4 u2 = *(const uint4*)(O2 + 8 * j);
        const unsigned int a[4] = {u1.x, u1.y, u1.z, u1.w};
        const unsigned int d[4] = {u2.x, u2.y, u2.z, u2.w};
        unsigned int ov[4];
#pragma unroll
        for (int q = 0; q < 4; q++) {
            const float y0 = bf2f((unsigned short)(a[q] & 0xffff)) * a1
                           + bf2f((unsigned short)(d[q] & 0xffff)) * a2;
            const float y1 = bf2f((unsigned short)(a[q] >> 16)) * a1
                           + bf2f((unsigned short)(d[q] >> 16)) * a2;
            ov[q] = pack2(y0, y1);
        }
        *(uint4*)(yrow + 8 * j) = make_uint4(ov[0], ov[1], ov[2], ov[3]);
    }
}

// ---------------------------------------------------------------------------
// Kernel 4: output projection. 64x128 tiles, BK=32, explicit LDS dbuf.
// grid (8, 64) = 512 blocks, block 256.
// ---------------------------------------------------------------------------
__global__ __launch_bounds__(256) void out_gemm(
    const unsigned short* __restrict__ A, const unsigned short* __restrict__ wcT,
    const float* __restrict__ bias, float* __restrict__ out)
{
    __shared__ unsigned short As[2][64 * 32];
    __shared__ unsigned short Bs[2][128 * 32];

    const int tid  = threadIdx.x;
    const int lane = tid & 63;
    const int wave = tid >> 6;
    const int n0 = blockIdx.x * 128;
    const int m0 = blockIdx.y * 64;

    const int lrow = lane >> 2, lch = (lane & 3) * 8;
    const unsigned short* agA = A   + (size_t)(m0 + wave * 16 + lrow) * K_ + lch;
    const unsigned short* bg0 = wcT + (size_t)(n0 + wave * 32 + lrow) * K_ + lch;
    const unsigned short* bg1 = bg0 + (size_t)16 * K_;
    const int ldsA  = (wave * 16) * 32;
    const int ldsB0 = (wave * 32) * 32;
    const int ldsB1 = (wave * 32 + 16) * 32;

    const int fr = lane & 15;
    const int fk = (lane >> 4) * 8;
    const int wr2 = wave >> 1, wc2 = wave & 1;

    floatx4 acc[2][4];
#pragma unroll
    for (int i = 0; i < 2; i++)
#pragma unroll
        for (int j = 0; j < 4; j++) acc[i][j] = (floatx4){0.f, 0.f, 0.f, 0.f};

    async16(agA, &As[0][ldsA]);
    async16(bg0, &Bs[0][ldsB0]);
    async16(bg1, &Bs[0][ldsB1]);

    for (int k0 = 0; k0 < K_; k0 += 32) {
        const int cur = (k0 >> 5) & 1;
        __syncthreads();
        if (k0 + 32 < K_) {
            const int nxt = cur ^ 1;
            async16(agA + k0 + 32, &As[nxt][ldsA]);
            async16(bg0 + k0 + 32, &Bs[nxt][ldsB0]);
            async16(bg1 + k0 + 32, &Bs[nxt][ldsB1]);
        }

        bf16x8 af[2], bfr[4];
#pragma unroll
        for (int i = 0; i < 2; i++)
            af[i] = *(const bf16x8*)&As[cur][(wr2 * 32 + i * 16 + fr) * 32 + fk];
#pragma unroll
        for (int j = 0; j < 4; j++)
            bfr[j] = *(const bf16x8*)&Bs[cur][(wc2 * 64 + j * 16 + fr) * 32 + fk];
#pragma unroll
        for (int i = 0; i < 2; i++)
#pragma unroll
            for (int j = 0; j < 4; j++)
                acc[i][j] = __builtin_amdgcn_mfma_f32_16x16x32_bf16(
                    af[i], bfr[j], acc[i][j], 0, 0, 0);
    }

    const int rbase = (lane >> 4) * 4;
#pragma unroll
    for (int j = 0; j < 4; j++) {
        const int col = n0 + wc2 * 64 + j * 16 + fr;
        const float bz = bias[col];
#pragma unroll
        for (int i = 0; i < 2; i++) {
#pragma unroll
            for (int pr = 0; pr < 4; pr++) {
                const int row = m0 + wr2 * 32 + i * 16 + rbase + pr;
                out[(size_t)row * N_ + col] = acc[i][j][pr] + bz;
            }
        }
    }
}

// ---------------------------------------------------------------------------
extern "C" void kernel_launch(void* const* d_in, const int* in_sizes, int n_in,
                              void* d_out, int out_size, void* d_ws, size_t ws_size,
                              hipStream_t stream) {
    const float* x  = (const float*)d_in[0];
    const float* wq = (const float*)d_in[1];
    const float* bq = (const float*)d_in[2];
    const float* wk = (const float*)d_in[3];
    const float* bk = (const float*)d_in[4];
    const float* wv = (const float*)d_in[5];
    const float* bv = (const float*)d_in[6];
    const float* wc = (const float*)d_in[7];
    const float* bc = (const float*)d_in[8];
    float* out = (float*)d_out;

    // ws (ushort units): qb 0, kb 4M, vb 8M, yb 12M, xb 16M, wT 20M..24M (48 MB)
    unsigned short* ws  = (unsigned short*)d_ws;
    unsigned short* qb  = ws;                        // [B,H,T,HS] rope+scale
    unsigned short* kb  = ws + (size_t)4194304;      // [B,H,T,HS] rope
    unsigned short* vb  = ws + (size_t)8388608;      // [B,H,HS,T] (V^T)
    unsigned short* yb  = ws + (size_t)12582912;     // [B,T,C]
    unsigned short* xb  = ws + (size_t)16777216;     // x bf16 (dead after qkv)
    unsigned short* wT  = ws + (size_t)20971520;     // 4x bf16 [n][k]
    unsigned short* wcT = wT + ((size_t)3 << 20);
    unsigned short* Opart = xb;                      // split-K O' partials
    float*          Mpart = (float*)wT;              // split-K m,l partials

    prep_kernel<<<5120, 256, 0, stream>>>(x, wq, wk, wv, wc, xb, wT);
    qkv_gemm<<<dim3(24, 64), 256, 0, stream>>>(xb, wT, bq, bk, bv, qb, kb, vb);
    attn_kernel<<<dim3(32, 48), 256, 0, stream>>>(qb, kb, vb, yb, Opart, Mpart);
    attn_combine<<<512, 256, 0, stream>>>(Opart, Mpart, yb);
    out_gemm<<<dim3(8, 64), 256, 0, stream>>>(yb, wcT, bc, out);
}

// Round 12
// 200.328 us; speedup vs baseline: 1.0446x; 1.0446x over previous
//
#include <hip/hip_runtime.h>

#define B_  2
#define T_  2048
#define C_  1024
#define H_  16
#define HS_ 64
#define M_  4096
#define N_  1024
#define K_  1024

typedef float floatx4 __attribute__((ext_vector_type(4)));
typedef short bf16x8  __attribute__((ext_vector_type(8)));

__device__ __forceinline__ float bf2f(unsigned short u) {
    return __uint_as_float(((unsigned int)u) << 16);
}
__device__ __forceinline__ unsigned short f2bf(float f) {
    unsigned int u = __float_as_uint(f);
    return (unsigned short)((u + 0x7fffu + ((u >> 16) & 1u)) >> 16);
}
__device__ __forceinline__ unsigned int pack2(float a, float b) {
    return (unsigned int)f2bf(a) | ((unsigned int)f2bf(b) << 16);
}
// truncating bf16 pair pack: one v_perm_b32
__device__ __forceinline__ unsigned int pack2t(float a, float b) {
    return __builtin_amdgcn_perm(__float_as_uint(b), __float_as_uint(a), 0x07060302u);
}
// async global->LDS, 16B per lane; lds dest = wave-uniform base + lane*16
__device__ __forceinline__ void async16(const unsigned short* g, unsigned short* l) {
    __builtin_amdgcn_global_load_lds(
        (const __attribute__((address_space(1))) unsigned int*)g,
        (__attribute__((address_space(3))) unsigned int*)l, 16, 0, 0);
}

// attn work table: 62 slots, LPT order (longest piece first).
// entry = (unit<<16)|(qt<<10)|(lo<<5)|hi ; unit=255 -> whole tile, write y.
// qt<=13 whole; 14<=qt<=25 split-2 (unit=(qt-14)*2+p);
// qt>=26 split-4 (unit=24+(qt-26)*4+p). 48 partial units per bh, 1536 total
// -> Opart 12 MB fits xb+wqT+wkT dead region (< wcT at 24.12M ushorts).
#define AE(u,q,lo,hi) (((u)<<16)|((q)<<10)|((lo)<<5)|(hi))
__device__ const unsigned int ATAB[62] = {
    AE(255,13,0,13),
    AE(255,12,0,12), AE(20,24,0,12), AE(22,25,0,12), AE(23,25,13,25),
    AE(255,11,0,11), AE(16,22,0,11), AE(18,23,0,11), AE(19,23,12,23), AE(21,24,13,24),
    AE(255,10,0,10), AE(12,20,0,10), AE(14,21,0,10), AE(15,21,11,21), AE(17,22,12,22),
    AE(255,9,0,9),   AE(8,18,0,9),   AE(10,19,0,9),  AE(11,19,10,19), AE(13,20,11,20),
    AE(255,8,0,8),   AE(4,16,0,8),   AE(6,17,0,8),   AE(7,17,9,17),   AE(9,18,10,18),
    AE(255,7,0,7),   AE(0,14,0,7),   AE(2,15,0,7),   AE(3,15,8,15),   AE(5,16,9,16),
    AE(32,28,0,7),   AE(36,29,0,7),  AE(37,29,8,15), AE(40,30,0,7),   AE(41,30,8,15),
    AE(42,30,16,23), AE(44,31,0,7),  AE(45,31,8,15), AE(46,31,16,23), AE(47,31,24,31),
    AE(255,6,0,6),   AE(1,14,8,14),  AE(24,26,0,6),  AE(25,26,7,13),  AE(26,26,14,20),
    AE(28,27,0,6),   AE(29,27,7,13), AE(30,27,14,20),AE(31,27,21,27), AE(33,28,8,14),
    AE(34,28,15,21), AE(35,28,22,28),AE(38,29,16,22),AE(39,29,23,29), AE(43,30,24,30),
    AE(255,5,0,5),   AE(27,26,21,26),
    AE(255,4,0,4),   AE(255,3,0,3),  AE(255,2,0,2),  AE(255,1,0,1),   AE(255,0,0,0)
};

// ---------------------------------------------------------------------------
// Prep (merged): blocks 0..4095 convert x fp32->bf16; blocks 4096..5119
// transpose+convert weights. grid 5120, block 256.
// ---------------------------------------------------------------------------
__global__ __launch_bounds__(256) void prep_kernel(
    const float* __restrict__ x,
    const float* __restrict__ w0, const float* __restrict__ w1,
    const float* __restrict__ w2, const float* __restrict__ w3,
    unsigned short* __restrict__ xb, unsigned short* __restrict__ wTall)
{
    __shared__ float tile[64][65];
    const int bid = blockIdx.x;
    const int t = threadIdx.x;
    if (bid < 4096) {
        const size_t i = ((size_t)bid * 256 + t) * 4;
        const float4 v = *(const float4*)(x + i);
        ushort4 st;
        st.x = f2bf(v.x); st.y = f2bf(v.y); st.z = f2bf(v.z); st.w = f2bf(v.w);
        *(ushort4*)(xb + i) = st;
        return;
    }
    const int zb = bid - 4096;
    const int z = zb >> 8, rem = zb & 255;
    const float* w = (z == 0) ? w0 : (z == 1) ? w1 : (z == 2) ? w2 : w3;
    unsigned short* wT = wTall + ((size_t)z << 20);
    const int n0 = (rem & 15) * 64, k0 = (rem >> 4) * 64;

    const int r = t >> 2, cq = (t & 3) * 16;
    const float4* src = (const float4*)(w + (size_t)(k0 + r) * N_ + n0 + cq);
    const float4 v0 = src[0], v1 = src[1], v2 = src[2], v3 = src[3];
    tile[r][cq+0]=v0.x; tile[r][cq+1]=v0.y; tile[r][cq+2]=v0.z; tile[r][cq+3]=v0.w;
    tile[r][cq+4]=v1.x; tile[r][cq+5]=v1.y; tile[r][cq+6]=v1.z; tile[r][cq+7]=v1.w;
    tile[r][cq+8]=v2.x; tile[r][cq+9]=v2.y; tile[r][cq+10]=v2.z; tile[r][cq+11]=v2.w;
    tile[r][cq+12]=v3.x; tile[r][cq+13]=v3.y; tile[r][cq+14]=v3.z; tile[r][cq+15]=v3.w;
    __syncthreads();

    const int rn = t >> 2, ck = (t & 3) * 16;
    unsigned int o[8];
#pragma unroll
    for (int ii = 0; ii < 8; ii++)
        o[ii] = pack2(tile[ck + 2*ii][rn], tile[ck + 2*ii + 1][rn]);
    unsigned short* dst = wT + (size_t)(n0 + rn) * K_ + k0 + ck;
    *(uint4*)dst       = make_uint4(o[0], o[1], o[2], o[3]);
    *(uint4*)(dst + 8) = make_uint4(o[4], o[5], o[6], o[7]);
}

// ---------------------------------------------------------------------------
// Kernel 1: fused QKV GEMM + RoPE. 64x128 tiles, BK=32, LDS double-buffer.
// grid (24, 64), block 256. (best measured variant)
// ---------------------------------------------------------------------------
__global__ __launch_bounds__(256) void qkv_gemm(
    const unsigned short* __restrict__ xb, const unsigned short* __restrict__ wT,
    const float* __restrict__ bq, const float* __restrict__ bk,
    const float* __restrict__ bv,
    unsigned short* __restrict__ qb, unsigned short* __restrict__ kb,
    unsigned short* __restrict__ vb)
{
    __shared__ unsigned short As[2][64 * 32];
    __shared__ unsigned short Bs[2][128 * 32];

    const int tid  = threadIdx.x;
    const int lane = tid & 63;
    const int wave = tid >> 6;
    const int p  = blockIdx.x >> 3;
    const int n0 = (blockIdx.x & 7) * 128;
    const int m0 = blockIdx.y * 64;
    const float* bias = (p == 0) ? bq : (p == 1) ? bk : bv;

    const int lrow = lane >> 2, lch = (lane & 3) * 8;
    const unsigned short* agA = xb + (size_t)(m0 + wave * 16 + lrow) * K_ + lch;
    const unsigned short* wb  = wT + ((size_t)p << 20);
    const unsigned short* bg0 = wb + (size_t)(n0 + wave * 32 + lrow) * K_ + lch;
    const unsigned short* bg1 = bg0 + (size_t)16 * K_;
    const int ldsA  = (wave * 16) * 32;
    const int ldsB0 = (wave * 32) * 32;
    const int ldsB1 = (wave * 32 + 16) * 32;

    const int fr = lane & 15;
    const int fk = (lane >> 4) * 8;
    const int wr2 = wave >> 1, wc2 = wave & 1;

    floatx4 acc[2][4];
#pragma unroll
    for (int i = 0; i < 2; i++)
#pragma unroll
        for (int j = 0; j < 4; j++) acc[i][j] = (floatx4){0.f, 0.f, 0.f, 0.f};

    async16(agA, &As[0][ldsA]);
    async16(bg0, &Bs[0][ldsB0]);
    async16(bg1, &Bs[0][ldsB1]);

    for (int k0 = 0; k0 < K_; k0 += 32) {
        const int cur = (k0 >> 5) & 1;
        __syncthreads();
        if (k0 + 32 < K_) {
            const int nxt = cur ^ 1;
            async16(agA + k0 + 32, &As[nxt][ldsA]);
            async16(bg0 + k0 + 32, &Bs[nxt][ldsB0]);
            async16(bg1 + k0 + 32, &Bs[nxt][ldsB1]);
        }

        bf16x8 af[2], bfr[4];
#pragma unroll
        for (int i = 0; i < 2; i++)
            af[i] = *(const bf16x8*)&As[cur][(wr2 * 32 + i * 16 + fr) * 32 + fk];
#pragma unroll
        for (int j = 0; j < 4; j++)
            bfr[j] = *(const bf16x8*)&Bs[cur][(wc2 * 64 + j * 16 + fr) * 32 + fk];
#pragma unroll
        for (int i = 0; i < 2; i++)
#pragma unroll
            for (int j = 0; j < 4; j++)
                acc[i][j] = __builtin_amdgcn_mfma_f32_16x16x32_bf16(
                    af[i], bfr[j], acc[i][j], 0, 0, 0);
    }

    const int rbase = (lane >> 4) * 4;
    const int h = (n0 + wc2 * 64) >> 6;
    if (p == 2) {    // V transposed: [B,H,HS,T]
#pragma unroll
        for (int j = 0; j < 4; j++) {
            const int col = n0 + wc2 * 64 + j * 16 + fr;
            const float bz = bias[col];
            const int d = col & 63;
#pragma unroll
            for (int i = 0; i < 2; i++) {
                const int row0 = m0 + wr2 * 32 + i * 16 + rbase;
                const int bb = row0 >> 11, tt = row0 & 2047;
                ushort4 st;
                st.x = f2bf(acc[i][j][0] + bz);
                st.y = f2bf(acc[i][j][1] + bz);
                st.z = f2bf(acc[i][j][2] + bz);
                st.w = f2bf(acc[i][j][3] + bz);
                *(ushort4*)&vb[((size_t)(bb * H_ + h) * HS_ + d) * T_ + tt] = st;
            }
        }
    } else {
        unsigned short* out = (p == 0) ? qb : kb;
        const float qsc = (p == 0) ? 0.18033688011111772f : 1.0f;  // 0.125*log2(e)
        const float bz0 = bias[n0 + wc2 * 64 + fr];
        const float bz1 = bias[n0 + wc2 * 64 + 16 + fr];
        const float bz2 = bias[n0 + wc2 * 64 + 32 + fr];
        const float bz3 = bias[n0 + wc2 * 64 + 48 + fr];
        const float nl = -0.41524101186279297f;   // -log2(10000)/32
        const float if0 = exp2f((float)fr * nl);
        const float if1 = exp2f((float)(fr + 16) * nl);
#pragma unroll
        for (int i = 0; i < 2; i++) {
#pragma unroll
            for (int pr = 0; pr < 4; pr++) {
                const int row = m0 + wr2 * 32 + i * 16 + rbase + pr;
                const int bb = row >> 11, tt = row & 2047;
                float s0, c0, s1, c1;
                __sincosf((float)tt * if0, &s0, &c0);
                __sincosf((float)tt * if1, &s1, &c1);
                const float v0 = acc[i][0][pr] + bz0;
                const float v1 = acc[i][1][pr] + bz1;
                const float v2 = acc[i][2][pr] + bz2;
                const float v3 = acc[i][3][pr] + bz3;
                unsigned short* ob = out + ((size_t)(bb * H_ + h) * T_ + tt) * HS_ + fr;
                ob[0]  = f2bf((v0 * c0 - v2 * s0) * qsc);
                ob[16] = f2bf((v1 * c1 - v3 * s1) * qsc);
                ob[32] = f2bf((v2 * c0 + v0 * s0) * qsc);
                ob[48] = f2bf((v3 * c1 + v1 * s1) * qsc);
            }
        }
    }
}

// ---------------------------------------------------------------------------
// Kernel 3: MFMA flash attention; work decoded from ATAB. grid (32, 62).
// ---------------------------------------------------------------------------
__global__ __launch_bounds__(256) void attn_kernel(
    const unsigned short* __restrict__ qb, const unsigned short* __restrict__ kb,
    const unsigned short* __restrict__ vt, unsigned short* __restrict__ yb,
    unsigned short* __restrict__ Opart, float* __restrict__ Mpart)
{
    __shared__ unsigned short Ks[2][64 * 64];
    __shared__ unsigned short Vs[2][64 * 64];
    __shared__ unsigned short Ps[4][16 * 64];

    const int bh = blockIdx.x;
    const int b = bh >> 4, h = bh & 15;
    const unsigned int e = ATAB[blockIdx.y];
    const int unit = (int)(e >> 16);
    const int qt   = (int)((e >> 10) & 63);
    const int ktlo = (int)((e >> 5) & 31);
    const int kthi = (int)(e & 31);
    const bool split = (unit != 255);

    const int r0 = qt * 64;
    const int tid  = threadIdx.x;
    const int lane = tid & 63;
    const int wave = tid >> 6;
    const int l4   = lane & 15;
    const int quad = lane >> 4;

    const int qrow_g = r0 + wave * 16 + l4;

    bf16x8 qf[2];
    {
        const unsigned short* qp = qb + ((size_t)bh * T_ + qrow_g) * HS_ + quad * 8;
        qf[0] = *(const bf16x8*)(qp);
        qf[1] = *(const bf16x8*)(qp + 32);
    }

    floatx4 o[4];
#pragma unroll
    for (int g = 0; g < 4; g++) o[g] = (floatx4){0.f, 0.f, 0.f, 0.f};
    float m = -1e30f, l = 0.f;

    const int srow = tid >> 2;
    const int sc16 = (tid & 3) * 16;
    const int ssw  = (srow & 7) * 8;
    const int psw  = (l4 & 7) * 8;

    const unsigned short* kp = kb + ((size_t)bh * T_ + srow) * HS_ + sc16;
    const unsigned short* vp = vt + ((size_t)(bh * 64 + srow)) * T_ + sc16;

    uint4 rk0 = *(const uint4*)(kp + (size_t)ktlo * 64 * HS_);
    uint4 rk1 = *(const uint4*)(kp + (size_t)ktlo * 64 * HS_ + 8);
    uint4 rv0 = *(const uint4*)(vp + ktlo * 64);
    uint4 rv1 = *(const uint4*)(vp + ktlo * 64 + 8);
    *(uint4*)&Ks[0][srow * 64 + ( sc16      ^ ssw)] = rk0;
    *(uint4*)&Ks[0][srow * 64 + ((sc16 + 8) ^ ssw)] = rk1;
    *(uint4*)&Vs[0][srow * 64 + ( sc16      ^ ssw)] = rv0;
    *(uint4*)&Vs[0][srow * 64 + ((sc16 + 8) ^ ssw)] = rv1;

    for (int kt = ktlo; kt <= kthi; kt++) {
        const int cur = (kt - ktlo) & 1;
        if (kt < kthi) {   // register prefetch of next tile
            const unsigned short* kpn = kp + (size_t)(kt + 1) * (64 * HS_);
            const unsigned short* vpn = vp + (kt + 1) * 64;
            rk0 = *(const uint4*)kpn;
            rk1 = *(const uint4*)(kpn + 8);
            rv0 = *(const uint4*)vpn;
            rv1 = *(const uint4*)(vpn + 8);
        }
        __syncthreads();

        floatx4 sf[4];
#pragma unroll
        for (int mg = 0; mg < 4; mg++) {
            const int key = mg * 16 + l4;
            const int ksw = (key & 7) * 8;
            const bf16x8 a0 = *(const bf16x8*)&Ks[cur][key * 64 + ( (quad * 8)       ^ ksw)];
            const bf16x8 a1 = *(const bf16x8*)&Ks[cur][key * 64 + (((quad * 8) + 32) ^ ksw)];
            floatx4 z = (floatx4){0.f, 0.f, 0.f, 0.f};
            z = __builtin_amdgcn_mfma_f32_16x16x32_bf16(a0, qf[0], z, 0, 0, 0);
            z = __builtin_amdgcn_mfma_f32_16x16x32_bf16(a1, qf[1], z, 0, 0, 0);
            sf[mg] = z;
        }

        if (kt == qt) {   // causal mask on diagonal tile
#pragma unroll
            for (int mg = 0; mg < 4; mg++)
#pragma unroll
                for (int r = 0; r < 4; r++)
                    if (kt * 64 + 16 * mg + quad * 4 + r > qrow_g)
                        sf[mg][r] = -1e30f;
        }

        float tm = sf[0][0];
#pragma unroll
        for (int mg = 0; mg < 4; mg++)
#pragma unroll
            for (int r = 0; r < 4; r++) tm = fmaxf(tm, sf[mg][r]);
        tm = fmaxf(tm, __shfl_xor(tm, 16));
        tm = fmaxf(tm, __shfl_xor(tm, 32));
        const float mnew  = fmaxf(m, tm);
        const float alpha = __builtin_amdgcn_exp2f(m - mnew);

        float p[4][4];
        float ps = 0.f;
#pragma unroll
        for (int mg = 0; mg < 4; mg++)
#pragma unroll
            for (int r = 0; r < 4; r++) {
                p[mg][r] = __builtin_amdgcn_exp2f(sf[mg][r] - mnew);
                ps += p[mg][r];
            }
        ps += __shfl_xor(ps, 16);
        ps += __shfl_xor(ps, 32);
        l = l * alpha + ps;
        m = mnew;
#pragma unroll
        for (int g = 0; g < 4; g++) o[g] = o[g] * alpha;

#pragma unroll
        for (int mg = 0; mg < 4; mg++) {
            const int kb4 = 16 * mg + quad * 4;
            const int off = ((kb4 & ~7) ^ psw) | (kb4 & 7);
            uint2 w;
            w.x = pack2t(p[mg][0], p[mg][1]);
            w.y = pack2t(p[mg][2], p[mg][3]);
            *(uint2*)&Ps[wave][l4 * 64 + off] = w;
        }

        const bf16x8 pf0 = *(const bf16x8*)&Ps[wave][l4 * 64 + ( (quad * 8)       ^ psw)];
        const bf16x8 pf1 = *(const bf16x8*)&Ps[wave][l4 * 64 + (((quad * 8) + 32) ^ psw)];
#pragma unroll
        for (int g = 0; g < 4; g++) {
            const int vd  = g * 16 + l4;
            const int vsw = (vd & 7) * 8;
            const bf16x8 va0 = *(const bf16x8*)&Vs[cur][vd * 64 + ( (quad * 8)       ^ vsw)];
            const bf16x8 va1 = *(const bf16x8*)&Vs[cur][vd * 64 + (((quad * 8) + 32) ^ vsw)];
            o[g] = __builtin_amdgcn_mfma_f32_16x16x32_bf16(va0, pf0, o[g], 0, 0, 0);
            o[g] = __builtin_amdgcn_mfma_f32_16x16x32_bf16(va1, pf1, o[g], 0, 0, 0);
        }

        if (kt < kthi) {
            const int nxt = cur ^ 1;
            *(uint4*)&Ks[nxt][srow * 64 + ( sc16      ^ ssw)] = rk0;
            *(uint4*)&Ks[nxt][srow * 64 + ((sc16 + 8) ^ ssw)] = rk1;
            *(uint4*)&Vs[nxt][srow * 64 + ( sc16      ^ ssw)] = rv0;
            *(uint4*)&Vs[nxt][srow * 64 + ((sc16 + 8) ^ ssw)] = rv1;
        }
    }

    if (!split) {
        const float invl = 1.f / l;
        unsigned short* yrow = yb + ((size_t)(b * T_ + qrow_g) * H_ + h) * HS_;
#pragma unroll
        for (int g = 0; g < 4; g++) {
            ushort4 st;
            st.x = f2bf(o[g][0] * invl);
            st.y = f2bf(o[g][1] * invl);
            st.z = f2bf(o[g][2] * invl);
            st.w = f2bf(o[g][3] * invl);
            *(ushort4*)&yrow[16 * g + quad * 4] = st;
        }
    } else {
        const int u  = bh * 48 + unit;
        const int rl = wave * 16 + l4;
        unsigned short* Op = Opart + (size_t)u * 4096 + rl * 64;
#pragma unroll
        for (int g = 0; g < 4; g++) {
            ushort4 st;
            st.x = f2bf(o[g][0]);
            st.y = f2bf(o[g][1]);
            st.z = f2bf(o[g][2]);
            st.w = f2bf(o[g][3]);
            *(ushort4*)&Op[16 * g + quad * 4] = st;
        }
        if (quad == 0) {
            float* ml = Mpart + (size_t)u * 128;
            ml[rl]      = m;
            ml[64 + rl] = l;
        }
    }
}

// ---------------------------------------------------------------------------
// Kernel 3b: merge 2- or 4-way split partials. grid (18, 32): x=qt-14, y=bh.
// ---------------------------------------------------------------------------
__global__ __launch_bounds__(256) void attn_combine(
    const unsigned short* __restrict__ Opart, const float* __restrict__ Mpart,
    unsigned short* __restrict__ yb)
{
    const int qt = 14 + (int)blockIdx.x;
    const int bh = (int)blockIdx.y;
    const int b = bh >> 4, h = bh & 15;
    const int np = (qt < 26) ? 2 : 4;
    const int ub = bh * 48 + ((qt < 26) ? (qt - 14) * 2 : 24 + (qt - 26) * 4);
    const int t = threadIdx.x;
    const int r = t >> 2, c = (t & 3) * 16;

    float mi[4], li[4], wi[4];
    float M = -1e30f;
    for (int i = 0; i < np; i++) {
        const float* ml = Mpart + (size_t)(ub + i) * 128;
        mi[i] = ml[r]; li[i] = ml[64 + r];
        M = fmaxf(M, mi[i]);
    }
    float L = 0.f;
    for (int i = 0; i < np; i++) {
        wi[i] = __builtin_amdgcn_exp2f(mi[i] - M);
        L += li[i] * wi[i];
    }
    const float inv = 1.f / L;

    float acc[16];
#pragma unroll
    for (int q = 0; q < 16; q++) acc[q] = 0.f;
    for (int i = 0; i < np; i++) {
        const float a = wi[i] * inv;
        const unsigned short* O = Opart + (size_t)(ub + i) * 4096 + r * 64 + c;
#pragma unroll
        for (int j = 0; j < 2; j++) {
            const uint4 u1 = *(const uint4*)(O + 8 * j);
            const unsigned int uv[4] = {u1.x, u1.y, u1.z, u1.w};
#pragma unroll
            for (int q = 0; q < 4; q++) {
                acc[j*8 + 2*q]     += bf2f((unsigned short)(uv[q] & 0xffff)) * a;
                acc[j*8 + 2*q + 1] += bf2f((unsigned short)(uv[q] >> 16)) * a;
            }
        }
    }
    unsigned short* yrow = yb + ((size_t)(b * T_ + qt * 64 + r) * H_ + h) * HS_ + c;
#pragma unroll
    for (int j = 0; j < 2; j++) {
        uint4 ov;
        ov.x = pack2(acc[j*8+0], acc[j*8+1]);
        ov.y = pack2(acc[j*8+2], acc[j*8+3]);
        ov.z = pack2(acc[j*8+4], acc[j*8+5]);
        ov.w = pack2(acc[j*8+6], acc[j*8+7]);
        *(uint4*)(yrow + 8 * j) = ov;
    }
}

// ---------------------------------------------------------------------------
// Kernel 4: output projection. 64x128 tiles, BK=64 two-stage (round-9 best).
// grid (8, 64), block 256.
// ---------------------------------------------------------------------------
__global__ __launch_bounds__(256) void out_gemm(
    const unsigned short* __restrict__ A, const unsigned short* __restrict__ wcT,
    const float* __restrict__ bias, float* __restrict__ out)
{
    __shared__ unsigned short As[2 * 64 * 32];    // [kh][m][k]
    __shared__ unsigned short Bs[2 * 128 * 32];   // [kh][n][k]

    const int tid  = threadIdx.x;
    const int lane = tid & 63;
    const int wave = tid >> 6;
    const int n0 = blockIdx.x * 128;
    const int m0 = blockIdx.y * 64;

    const int lrow = lane >> 2, lch = (lane & 3) * 8;
    const unsigned short* ag  = A   + (size_t)(m0 + wave * 16 + lrow) * K_ + lch;
    const unsigned short* bg0 = wcT + (size_t)(n0 + wave * 32 + lrow) * K_ + lch;
    const unsigned short* bg1 = bg0 + (size_t)16 * K_;
    unsigned short* lA0  = &As[(wave * 16) * 32];
    unsigned short* lA1  = lA0 + 2048;                 // kh=1
    unsigned short* lB00 = &Bs[(wave * 32) * 32];
    unsigned short* lB01 = &Bs[(wave * 32 + 16) * 32];
    unsigned short* lB10 = lB00 + 4096;
    unsigned short* lB11 = lB01 + 4096;

    const int fr = lane & 15;
    const int fk = (lane >> 4) * 8;
    const int wr2 = wave >> 1, wc2 = wave & 1;

    floatx4 acc[2][4];
#pragma unroll
    for (int i = 0; i < 2; i++)
#pragma unroll
        for (int j = 0; j < 4; j++) acc[i][j] = (floatx4){0.f, 0.f, 0.f, 0.f};

    for (int k0 = 0; k0 < K_; k0 += 64) {
        __syncthreads();
        async16(ag  + k0,      lA0);
        async16(ag  + k0 + 32, lA1);
        async16(bg0 + k0,      lB00);
        async16(bg1 + k0,      lB01);
        async16(bg0 + k0 + 32, lB10);
        async16(bg1 + k0 + 32, lB11);
        __syncthreads();

#pragma unroll
        for (int kh = 0; kh < 2; kh++) {
            const unsigned short* Ah = &As[kh * 2048];
            const unsigned short* Bh = &Bs[kh * 4096];
            bf16x8 af[2], bfr[4];
#pragma unroll
            for (int i = 0; i < 2; i++)
                af[i] = *(const bf16x8*)&Ah[(wr2 * 32 + i * 16 + fr) * 32 + fk];
#pragma unroll
            for (int j = 0; j < 4; j++)
                bfr[j] = *(const bf16x8*)&Bh[(wc2 * 64 + j * 16 + fr) * 32 + fk];
#pragma unroll
            for (int i = 0; i < 2; i++)
#pragma unroll
                for (int j = 0; j < 4; j++)
                    acc[i][j] = __builtin_amdgcn_mfma_f32_16x16x32_bf16(
                        af[i], bfr[j], acc[i][j], 0, 0, 0);
        }
    }

    const int rbase = (lane >> 4) * 4;
#pragma unroll
    for (int j = 0; j < 4; j++) {
        const int col = n0 + wc2 * 64 + j * 16 + fr;
        const float bz = bias[col];
#pragma unroll
        for (int i = 0; i < 2; i++) {
#pragma unroll
            for (int pr = 0; pr < 4; pr++) {
                const int row = m0 + wr2 * 32 + i * 16 + rbase + pr;
                out[(size_t)row * N_ + col] = acc[i][j][pr] + bz;
            }
        }
    }
}

// ---------------------------------------------------------------------------
extern "C" void kernel_launch(void* const* d_in, const int* in_sizes, int n_in,
                              void* d_out, int out_size, void* d_ws, size_t ws_size,
                              hipStream_t stream) {
    const float* x  = (const float*)d_in[0];
    const float* wq = (const float*)d_in[1];
    const float* bq = (const float*)d_in[2];
    const float* wk = (const float*)d_in[3];
    const float* bk = (const float*)d_in[4];
    const float* wv = (const float*)d_in[5];
    const float* bv = (const float*)d_in[6];
    const float* wc = (const float*)d_in[7];
    const float* bc = (const float*)d_in[8];
    float* out = (float*)d_out;

    // ws layout (ushort units), 48 MB total:
    //   qb 0..4M | kb 4M..8M | vb 8M..12M | yb 12M..16M | xb 16M..20M |
    //   wT 20M..24M (wqT,wkT,wvT,wcT; wcT at 24,117,248..25,165,824)
    // After qkv: xb+wqT+wkT dead -> Opart 1536x4096 = 6,291,456 ushorts at 16M
    //   (ends 23,068,672); Mpart 1536x128 fp32 = 393,216 ushorts at 23,068,672
    //   (ends 23,461,888 < wcT start 24,117,248). All in-bounds.
    unsigned short* ws  = (unsigned short*)d_ws;
    unsigned short* qb  = ws;                        // [B,H,T,HS] rope+scale
    unsigned short* kb  = ws + (size_t)4194304;      // [B,H,T,HS] rope
    unsigned short* vb  = ws + (size_t)8388608;      // [B,H,HS,T] (V^T)
    unsigned short* yb  = ws + (size_t)12582912;     // [B,T,C]
    unsigned short* xb  = ws + (size_t)16777216;     // x bf16 (dead after qkv)
    unsigned short* wT  = ws + (size_t)20971520;     // 4x bf16 [n][k]
    unsigned short* wcT = wT + ((size_t)3 << 20);
    unsigned short* Opart = xb;                                // 12 MB
    float*          Mpart = (float*)(ws + (size_t)23068672);   // 0.75 MB

    prep_kernel<<<5120, 256, 0, stream>>>(x, wq, wk, wv, wc, xb, wT);
    qkv_gemm<<<dim3(24, 64), 256, 0, stream>>>(xb, wT, bq, bk, bv, qb, kb, vb);
    attn_kernel<<<dim3(32, 62), 256, 0, stream>>>(qb, kb, vb, yb, Opart, Mpart);
    attn_combine<<<dim3(18, 32), 256, 0, stream>>>(Opart, Mpart, yb);
    out_gemm<<<dim3(8, 64), 256, 0, stream>>>(yb, wcT, bc, out);
}